// Round 6
// baseline (170.922 us; speedup 1.0000x reference)
//
#include <hip/hip_runtime.h>

// R16: transposed-gate wave-autonomous LSTM. B=4096, L=256, H=32, D=2.
// 2048 single-wave WGs x 64 thr; 8 WGs/CU (dyn-LDS capped, exact) -> 2
// independent waves/SIMD, zero barriers / zero LDS in the recurrence.
// Key change vs R14: gates computed TRANSPOSED, D = h @ Wh (batches on
// MFMA rows, gate-cols on cols). 8 tiles tt=0..7: tile tt covers gate-cols
// 32*(tt>>1) + 16*(tt&1) + m; A = h[batch row&1][unit 8oct+j] (2 batches
// x 8 row-dup). Lane (m,oct) owns cell u = m+16*(oct&1), b = oct>>1:
//  - its 4 gates sit at acc[2q+(oct&1)][oct>>1]: 12 cndmask (R14: 28).
//  - owner-lane map: cell (u,b) lives in lane (u&15) + 16*((u>>4)+2b);
//    adjacent-u pairs are lane^1 -> pack = cvt_pk + swizzle(xor1) + perm;
//    the 4 ds_bpermute results ARE the A-frag dwords (R14's 4 assembly
//    perms eliminated).
//  - head logits: 9th MFMA with Wo as B (cols 0,1) -> lane m<2,oct==0
//    holds S(b=r)[m] in accO[r]; 2 ds_write_b32 to Sbuf.
//  - bias+Wi*spin: 4 fmaf (off-chain) + 4 adds post-select.
// Cell math (combined-rcp, 7 transcendentals), spin pair prefetch, post
// ELU/log-softmax carried from R14. Dynamic LDS pad 15616 B -> 20.3KB/WG
// -> exactly 8 WGs/CU (dynamic can't be DCE'd like R15's static pad).

typedef __attribute__((ext_vector_type(8))) short bf16x8;
typedef __attribute__((ext_vector_type(4))) float f32x4;
typedef __attribute__((ext_vector_type(4))) unsigned int u32x4;

#define LOG2E 1.4426950408889634f
#define LN2   0.6931471805599453f

__device__ __forceinline__ float fexp2(float x) { return __builtin_amdgcn_exp2f(x); }
__device__ __forceinline__ float flog2(float x) { return __builtin_amdgcn_logf(x); }
__device__ __forceinline__ float frcp(float x)  { return __builtin_amdgcn_rcpf(x); }

__device__ __forceinline__ float fsig(float x)   { return frcp(1.f + fexp2(-LOG2E * x)); }
__device__ __forceinline__ float ftanh_(float x) { return 1.f - 2.f * frcp(fexp2(2.f * LOG2E * x) + 1.f); }
__device__ __forceinline__ float felu(float x)   { return x > 0.f ? x : fexp2(LOG2E * x) - 1.f; }

__device__ __forceinline__ unsigned short f2bf(float f) {   // RNE f32->bf16
    unsigned u = __builtin_bit_cast(unsigned, f);
    u = (u + 0x7FFFu + ((u >> 16) & 1u)) >> 16;
    return (unsigned short)u;
}

__device__ __forceinline__ unsigned cvtpk_bf16(float a, float b) {
    unsigned r;
    asm("v_cvt_pk_bf16_f32 %0, %1, %2" : "=v"(r) : "v"(a), "v"(b));
    return r;   // lo16 = bf16(a), hi16 = bf16(b), RNE
}

constexpr int Bsz = 4096;

__global__ __launch_bounds__(64, 2) void lstm_r16(
    const int*   __restrict__ x,    // [B, 256]
    const float* __restrict__ Wi,   // [2, 128]
    const float* __restrict__ Wh,   // [32, 128]
    const float* __restrict__ bh,   // [128]
    const float* __restrict__ Wo,   // [32, 2]
    const float* __restrict__ bo,   // [2]
    float*       __restrict__ out)  // [B]
{
    const int lane = threadIdx.x;   // single wave
    const int m    = lane & 15;     // MFMA column
    const int oct  = lane >> 4;
    const int pa   = oct & 1;       // unit-half bit
    const int bb   = oct >> 1;      // this lane's cell batch
    const int b0   = blockIdx.x * 2;

    extern __shared__ char dynpad[];          // occupancy cap (can't be DCE'd)
    __shared__ char   spinT[2][260];          // [batch][t] bytes, padded row
    __shared__ float2 Sbuf[256][2];           // raw logits (S0,S1) per (t,batch)
    if (blockIdx.x == 0xFFFFFFFFu) dynpad[0] = 1;

    // ---- stage spins: 64 threads x 8 bytes (2 rows x 256) ----
    {
        const int bl = lane >> 5;            // row 0..1
        const int c8 = (lane & 31) * 8;
        const int4* src = reinterpret_cast<const int4*>(x + (b0 + bl) * 256 + c8);
        const int4 v0 = src[0], v1 = src[1];
        const int p0 = (v0.x & 1) | ((v0.y & 1) << 8) | ((v0.z & 1) << 16) | ((v0.w & 1) << 24);
        const int p1 = (v1.x & 1) | ((v1.y & 1) << 8) | ((v1.z & 1) << 16) | ((v1.w & 1) << 24);
        *reinterpret_cast<int*>(&spinT[bl][c8])     = p0;
        *reinterpret_cast<int*>(&spinT[bl][c8 + 4]) = p1;
    }

    // ---- B-frags (weights): tile tt covers gate-col 32*(tt>>1)+16*(tt&1)+m
    bf16x8 wfrag[8];
#pragma unroll
    for (int tt = 0; tt < 8; ++tt) {
        const int q = tt >> 1;
        const float gs = (q == 2) ? 2.f * LOG2E : -LOG2E;
        const int colg = 32 * q + 16 * (tt & 1) + m;
#pragma unroll
        for (int j = 0; j < 8; ++j)
            wfrag[tt][j] = (short)f2bf(gs * Wh[(8 * oct + j) * 128 + colg]);
    }
    bf16x8 wfragO;   // head: Wo as B-operand cols 0,1
#pragma unroll
    for (int j = 0; j < 8; ++j)
        wfragO[j] = (m < 2) ? (short)f2bf(Wo[(8 * oct + j) * 2 + m]) : (short)0;

    // ---- this lane's cell + scaled biases ----
    const int u = m + 16 * pa;
    float bv0[4], bvd[4];
#pragma unroll
    for (int q = 0; q < 4; ++q) {
        const float gs = (q == 2) ? 2.f * LOG2E : -LOG2E;
        const int c0 = 32 * q + u;
        bv0[q] = gs * (bh[c0] + Wi[c0]);
        bvd[q] = gs * (Wi[128 + c0] - Wi[c0]);
    }
    const float bo0 = bo[0], bo1 = bo[1];

    // ---- exchange constants ----
    // A-frag dword i = h[m&1][8oct+2i .. +2i+1]; owner-pair base lane:
    const int ab  = 8 * pa + 16 * bb + 32 * (m & 1);
    const int ad0 = 4 * (ab + 0), ad1 = 4 * (ab + 2);
    const int ad2 = 4 * (ab + 4), ad3 = 4 * (ab + 6);
    // pack selector: even lane owns u even -> p = own | neighbor<<16
    const unsigned selv = (lane & 1) ? 0x01000504u : 0x05040100u;

    __syncthreads();   // spins staged

    // ---- peel t=0: input zeros, h=c=0 -> gates = bh ----
    float c = fsig(bh[u]) * ftanh_(bh[64 + u]);
    unsigned p;
    {
        const float h0 = fsig(bh[96 + u]) * ftanh_(c);
        const unsigned r32 = cvtpk_bf16(h0, h0);
        const unsigned sw  = (unsigned)__builtin_amdgcn_ds_swizzle((int)r32, 0x041F); // xor-1
        p = __builtin_amdgcn_perm(sw, r32, selv);
    }

    const f32x4 zero4 = { 0.f, 0.f, 0.f, 0.f };

    auto step = [&](const int t, const float spf) {
        // exchange-in: the 4 gathered dwords ARE the A-frag
        const int G0 = __builtin_amdgcn_ds_bpermute(ad0, (int)p);
        const int G1 = __builtin_amdgcn_ds_bpermute(ad1, (int)p);
        const int G2 = __builtin_amdgcn_ds_bpermute(ad2, (int)p);
        const int G3 = __builtin_amdgcn_ds_bpermute(ad3, (int)p);

        // bias (overlaps bpermute wait)
        const float cb0 = fmaf(spf, bvd[0], bv0[0]);
        const float cb1 = fmaf(spf, bvd[1], bv0[1]);
        const float cb2 = fmaf(spf, bvd[2], bv0[2]);
        const float cb3 = fmaf(spf, bvd[3], bv0[3]);

        u32x4 hv; hv[0] = (unsigned)G0; hv[1] = (unsigned)G1;
        hv[2] = (unsigned)G2; hv[3] = (unsigned)G3;
        const bf16x8 hfrag = __builtin_bit_cast(bf16x8, hv);

        f32x4 acc[8];
#pragma unroll
        for (int tt = 0; tt < 8; ++tt)
            acc[tt] = __builtin_amdgcn_mfma_f32_16x16x32_bf16(hfrag, wfrag[tt], zero4, 0, 0, 0);
        const f32x4 accO = __builtin_amdgcn_mfma_f32_16x16x32_bf16(hfrag, wfragO, zero4, 0, 0, 0);
        if (oct == 0 && m < 2) {   // S(t-1): rows r=0,1 = batches 0,1; col m
            reinterpret_cast<float*>(&Sbuf[t - 1][0])[m] = accO[0];
            reinterpret_cast<float*>(&Sbuf[t - 1][1])[m] = accO[1];
        }

        // gate select: acc[2q+pa][bb]  (3 cndmask per gate)
        float ge[4];
#pragma unroll
        for (int q = 0; q < 4; ++q) {
            const float t0 = bb ? acc[2 * q][1]     : acc[2 * q][0];
            const float t1 = bb ? acc[2 * q + 1][1] : acc[2 * q + 1][0];
            ge[q] = pa ? t1 : t0;
        }

        // cell update: e_i=e^{-i}, e_f=e^{-f}, e_g=e^{2g}, e_o=e^{-o}
        const float a0 = cb0 + ge[0];
        const float a1 = cb1 + ge[1];
        const float a2 = cb2 + ge[2];
        const float a3 = cb3 + ge[3];
        const float ei = fexp2(a0), ef = fexp2(a1);
        const float eg = fexp2(a2), eo = fexp2(a3);
        const float P = (1.f + ei) * (1.f + eg);
        const float Q = 1.f + ef;
        const float R = frcp(P * Q);
        c = fmaf(P * R, c, (eg - 1.f) * Q * R);
        const float ec = fexp2(2.f * LOG2E * c);
        const float h  = (ec - 1.f) * frcp((1.f + eo) * (1.f + ec));

        // exchange-out: pack adjacent-u pair (lane^1)
        const unsigned r32 = cvtpk_bf16(h, h);
        const unsigned sw  = (unsigned)__builtin_amdgcn_ds_swizzle((int)r32, 0x041F);
        p = __builtin_amdgcn_perm(sw, r32, selv);
    };

    // spins for pair (tb, tb+1) = bytes (tb-1, tb), prefetched a pair ahead
    unsigned sp2 = *reinterpret_cast<const unsigned short*>(&spinT[bb][0]);
    for (int tb = 1; tb < 255; tb += 2) {
        const unsigned sp2n =
            *reinterpret_cast<const unsigned short*>(&spinT[bb][tb + 1]);
        step(tb,     (float)(sp2 & 0xFFu));
        step(tb + 1, (float)(sp2 >> 8));
        sp2 = sp2n;
    }
    step(255, (float)(sp2 & 0xFFu));   // uses spin 254

    // ---- tail: head logits of step 255 from h_255 ----
    {
        const int G0 = __builtin_amdgcn_ds_bpermute(ad0, (int)p);
        const int G1 = __builtin_amdgcn_ds_bpermute(ad1, (int)p);
        const int G2 = __builtin_amdgcn_ds_bpermute(ad2, (int)p);
        const int G3 = __builtin_amdgcn_ds_bpermute(ad3, (int)p);
        u32x4 hv; hv[0] = (unsigned)G0; hv[1] = (unsigned)G1;
        hv[2] = (unsigned)G2; hv[3] = (unsigned)G3;
        const bf16x8 hfrag = __builtin_bit_cast(bf16x8, hv);
        const f32x4 accO = __builtin_amdgcn_mfma_f32_16x16x32_bf16(hfrag, wfragO, zero4, 0, 0, 0);
        if (oct == 0 && m < 2) {
            reinterpret_cast<float*>(&Sbuf[255][0])[m] = accO[0];
            reinterpret_cast<float*>(&Sbuf[255][1])[m] = accO[1];
        }
    }
    __syncthreads();

    // ---- post phase: ELU + log-softmax + sum over t ----
    float lp = 0.f;
    {
        const int bpost = lane & 1;     // batch
        const int tc    = lane >> 1;    // time chunk 0..31
#pragma unroll
        for (int i = 0; i < 8; ++i) {
            const int t = tc * 8 + i;
            const float2 sv = Sbuf[t][bpost];
            const int sp = spinT[bpost][t];
            const float o0 = felu(sv.x + bo0);
            const float o1 = felu(sv.y + bo1);
            const float mx = fmaxf(o0, o1), mn = fminf(o0, o1);
            const float lse = mx + LN2 * flog2(1.f + fexp2(LOG2E * (mn - mx)));
            lp += (sp ? o1 : o0) - lse;
        }
    }
    lp += __shfl_xor(lp, 2, 64);    // reduce over tc bits (keep batch bit 0)
    lp += __shfl_xor(lp, 4, 64);
    lp += __shfl_xor(lp, 8, 64);
    lp += __shfl_xor(lp, 16, 64);
    lp += __shfl_xor(lp, 32, 64);
    if (lane < 2) out[b0 + lane] = 0.5f * lp;
}

extern "C" void kernel_launch(void* const* d_in, const int* in_sizes, int n_in,
                              void* d_out, int out_size, void* d_ws, size_t ws_size,
                              hipStream_t stream) {
    const int*   x  = (const int*)d_in[0];
    const float* Wi = (const float*)d_in[1];
    const float* Wh = (const float*)d_in[2];
    const float* bh = (const float*)d_in[3];
    const float* Wo = (const float*)d_in[4];
    const float* bo = (const float*)d_in[5];
    float* out = (float*)d_out;

    // 2048 single-wave WGs; static (~4.7KB) + 15616B dynamic ≈ 20.3KB/WG
    // -> exactly 8 WGs/CU (163840/20320 = 8.06), grid 2048 = 8 x 256 CUs:
    // full-occupancy single dispatch wave, no tail, 2 indep waves/SIMD.
    lstm_r16<<<dim3(Bsz / 2), dim3(64), 15616, stream>>>(x, Wi, Wh, bh, Wo, bo, out);
}

// Round 7
// 136.908 us; speedup vs baseline: 1.2484x; 1.2484x over previous
//
#include <hip/hip_runtime.h>

// R17: R12 skeleton (4-wave WG, 8 batches, dup=2 gate tiles, LDS h-exchange,
// one barrier/step) + anti-phase-lock levers. B=4096, L=256, H=32, D=2.
// 512 WGs x 256 threads, EXACTLY 2 WGs/CU.
// R13-R16 established: LDS-exchange family is structurally best (787 cyc/step
// vs 1035-1160 for all crossbar variants); its wall = ~400 issue + ~390
// unhidden latency, and co-resident WGs PHASE-LOCK (R12 beat R10 by only 4%).
// Levers here:
//  1. LDS pad that cannot be DCE'd: Sbuf[256][28] (57KB) -> 60.8KB static/WG
//     -> 3 WGs/CU impossible; grid 512 = 2x256 uniform. (R12/R15/R16 pads
//     were all silently dropped - LDS_Block_Size showed static only.)
//  2. Anti-phase seeding: one-time s_sleep(6) (~384cy ~ half-period) for one
//     WG of each co-resident pair, keyed (blockIdx ^ blockIdx>>8)&1.
//  3. s_setprio(1) over the post-barrier critical region (ds_read -> MFMA ->
//     select), 0 during the latency-tolerant trans chain: arbitration favors
//     the data-ready WG, reinforcing anti-phase.
//  4. v_cvt_pk_bf16_f32 pack for the h write (1 instr vs 3).

typedef __attribute__((ext_vector_type(8))) short bf16x8;
typedef __attribute__((ext_vector_type(4))) float f32x4;

#define LOG2E 1.4426950408889634f
#define LN2   0.6931471805599453f

__device__ __forceinline__ float fexp2(float x) { return __builtin_amdgcn_exp2f(x); }
__device__ __forceinline__ float flog2(float x) { return __builtin_amdgcn_logf(x); }
__device__ __forceinline__ float frcp(float x)  { return __builtin_amdgcn_rcpf(x); }

__device__ __forceinline__ float fsig(float x)   { return frcp(1.f + fexp2(-LOG2E * x)); }
__device__ __forceinline__ float ftanh_(float x) { return 1.f - 2.f * frcp(fexp2(2.f * LOG2E * x) + 1.f); }
__device__ __forceinline__ float felu(float x)   { return x > 0.f ? x : fexp2(LOG2E * x) - 1.f; }

__device__ __forceinline__ unsigned short f2bf(float f) {   // RNE f32->bf16
    unsigned u = __builtin_bit_cast(unsigned, f);
    u = (u + 0x7FFFu + ((u >> 16) & 1u)) >> 16;
    return (unsigned short)u;
}

__device__ __forceinline__ unsigned cvtpk_bf16(float a, float b) {
    unsigned r;
    asm("v_cvt_pk_bf16_f32 %0, %1, %2" : "=v"(r) : "v"(a), "v"(b));
    return r;   // lo16 = bf16(a), hi16 = bf16(b), RNE
}

constexpr int Bsz = 4096;

__global__ __launch_bounds__(256, 2) void lstm_r17(
    const int*   __restrict__ x,    // [B, 256]
    const float* __restrict__ Wi,   // [2, 128]
    const float* __restrict__ Wh,   // [32, 128]
    const float* __restrict__ bh,   // [128]
    const float* __restrict__ Wo,   // [32, 2]
    const float* __restrict__ bo,   // [2]
    float*       __restrict__ out)  // [B]
{
    const int tid  = threadIdx.x;
    const int w    = tid >> 6;      // wave 0..3 == rotation
    const int lane = tid & 63;
    const int m    = lane & 15;     // MFMA column
    const int oct  = lane >> 4;
    const int rot  = w;
    const int mb   = m & 7;         // batch within WG
    const int hi   = m >> 3;        // unit half -> acc reg index
    const int b0   = blockIdx.x * 8;

    __shared__ char   spinT[8][260];      // [batch][t] bytes, padded row
    __shared__ float2 Sbuf[256][28];      // logits in cols 0..7; cols 8..27 =
                                          // occupancy pad (indexed array ->
                                          // not DCE-able): 60.8KB/WG total
    __shared__ short  hbuf[2][8][40];     // h dbuf, row stride 80 B
    __shared__ float  red[4][8];

    // ---- stage spins: 256 threads x 8 ints ----
    {
        const int bl = tid >> 5;          // 0..7
        const int c8 = (tid & 31) * 8;
        const int4* src = reinterpret_cast<const int4*>(x + (b0 + bl) * 256 + c8);
        const int4 v0 = src[0], v1 = src[1];
        const int p0 = (v0.x & 1) | ((v0.y & 1) << 8) | ((v0.z & 1) << 16) | ((v0.w & 1) << 24);
        const int p1 = (v1.x & 1) | ((v1.y & 1) << 8) | ((v1.z & 1) << 16) | ((v1.w & 1) << 24);
        *reinterpret_cast<int*>(&spinT[bl][c8])     = p0;
        *reinterpret_cast<int*>(&spinT[bl][c8 + 4]) = p1;
    }

    // ---- weight A-frags: tile q row 4a+r (r=m&3, a=m>>2):
    //   r in {0,1}: gate col 32q + 16r + 4a + rot (scaled)
    //   r in {2,3}, q==0: Wo col r-2 (raw) -> free head logits
    bf16x8 wfrag[4];
#pragma unroll
    for (int q = 0; q < 4; ++q) {
        const float gs = (q == 2) ? 2.f * LOG2E : -LOG2E;
        const int r = m & 3, a = m >> 2;
#pragma unroll
        for (int j = 0; j < 8; ++j) {
            float v = 0.f;
            if (r < 2)          v = gs * Wh[(oct * 8 + j) * 128 + (32 * q + 16 * r + 4 * a + rot)];
            else if (q == 0)    v = Wo[(oct * 8 + j) * 2 + (r - 2)];
            wfrag[q][j] = (short)f2bf(v);
        }
    }

    // ---- this lane's cell + scaled biases ----
    const int ucell = 4 * oct + rot + 16 * hi;
    float bv0[4], bvd[4];
#pragma unroll
    for (int q = 0; q < 4; ++q) {
        const float gs = (q == 2) ? 2.f * LOG2E : -LOG2E;
        const int c0 = 32 * q + ucell;
        bv0[q] = gs * (bh[c0] + Wi[c0]);
        bvd[q] = gs * (Wi[128 + c0] - Wi[c0]);
    }
    const float bo0 = bo[0], bo1 = bo[1];

    // ---- peel t=0: input zeros, h=c=0 -> gates = bh ----
    float c = fsig(bh[ucell]) * ftanh_(bh[64 + ucell]);
    hbuf[0][mb][ucell] = (short)f2bf(fsig(bh[96 + ucell]) * ftanh_(c));
    __syncthreads();

    // ---- anti-phase seed: offset one WG of each co-resident pair by
    // ~half a step period (384 cyc). Period is identical for both WGs, so
    // the offset persists and their issue/latency phases interleave.
    if ((blockIdx.x ^ (blockIdx.x >> 8)) & 1) __builtin_amdgcn_s_sleep(6);

    const int rotS = __builtin_amdgcn_readfirstlane(rot);
    const f32x4 zero4 = { 0.f, 0.f, 0.f, 0.f };

    // one step; rb/wb compile-time at each call site -> static addresses
    auto step = [&](const int t, const int rb, const int wb, const float spf) {
        __builtin_amdgcn_s_setprio(1);   // critical region: read->MFMA->select
        const bf16x8 hfrag =
            *reinterpret_cast<const bf16x8*>(&hbuf[rb][mb][8 * oct]);

        f32x4 acc[4];
#pragma unroll
        for (int q = 0; q < 4; ++q)
            acc[q] = __builtin_amdgcn_mfma_f32_16x16x32_bf16(wfrag[q], hfrag, zero4, 0, 0, 0);

        // head logits of step t-1 (Wo rows embedded in q=0 tile regs 2,3)
        if (rotS == ((t - 1) & 3)) {
            if (oct == 0 && m < 8)
                Sbuf[t - 1][m] = make_float2(acc[0][2], acc[0][3]);
        }

        // gate extract: reg r = hi (one cndmask each)
        const float g0 = hi ? acc[0][1] : acc[0][0];
        const float g1 = hi ? acc[1][1] : acc[1][0];
        const float g2 = hi ? acc[2][1] : acc[2][0];
        const float g3 = hi ? acc[3][1] : acc[3][0];
        __builtin_amdgcn_s_setprio(0);   // trans chain is latency-tolerant

        // cell update; e_i=e^{-i}, e_f=e^{-f}, e_g=e^{2g}, e_o=e^{-o};
        // combined reciprocal saves one rcp.
        const float a0 = fmaf(spf, bvd[0], bv0[0]) + g0;
        const float a1 = fmaf(spf, bvd[1], bv0[1]) + g1;
        const float a2 = fmaf(spf, bvd[2], bv0[2]) + g2;
        const float a3 = fmaf(spf, bvd[3], bv0[3]) + g3;
        const float ei = fexp2(a0), ef = fexp2(a1);
        const float eg = fexp2(a2), eo = fexp2(a3);
        const float P = (1.f + ei) * (1.f + eg);
        const float Q = 1.f + ef;
        const float R = frcp(P * Q);
        const float gf  = P * R;                 // 1/(1+ef)
        const float igt = (eg - 1.f) * Q * R;    // sig(i)*tanh(g)
        c = fmaf(gf, c, igt);
        const float ec = fexp2(2.f * LOG2E * c);
        const float h  = (ec - 1.f) * frcp((1.f + eo) * (1.f + ec));
        hbuf[wb][mb][ucell] = (short)cvtpk_bf16(h, h);   // 1-instr RNE pack
        __syncthreads();   // h_t visible to all waves of THIS WG only
    };

    // spins for pair (tb, tb+1) = bytes (tb-1, tb), prefetched a pair ahead
    unsigned sp2 = *reinterpret_cast<const unsigned short*>(&spinT[mb][0]);
    for (int tb = 1; tb < 255; tb += 2) {
        const unsigned sp2n =
            *reinterpret_cast<const unsigned short*>(&spinT[mb][tb + 1]);
        step(tb,     0, 1, (float)(sp2 & 0xFFu));
        step(tb + 1, 1, 0, (float)(sp2 >> 8));
        sp2 = sp2n;
    }
    step(255, 0, 1, (float)(sp2 & 0xFFu));   // uses spin 254

    // ---- tail: head logits of step 255 (h_255 in hbuf[1]) ----
    if (rotS == 0) {
        const bf16x8 hfrag = *reinterpret_cast<const bf16x8*>(&hbuf[1][mb][8 * oct]);
        const f32x4 hs =
            __builtin_amdgcn_mfma_f32_16x16x32_bf16(wfrag[0], hfrag, zero4, 0, 0, 0);
        if (oct == 0 && m < 8) Sbuf[255][m] = make_float2(hs[2], hs[3]);
    }
    __syncthreads();

    // ---- post phase: ELU + log-softmax + sum over t, 32 time-chunks ----
    float lp = 0.f;
    {
        const int t0 = ((w * 4 + oct) * 2 + hi) * 8;
#pragma unroll
        for (int i = 0; i < 8; ++i) {
            const int t = t0 + i;
            const float2 sv = Sbuf[t][mb];
            const int sp = spinT[mb][t];
            const float o0 = felu(sv.x + bo0);
            const float o1 = felu(sv.y + bo1);
            const float mx = fmaxf(o0, o1), mn = fminf(o0, o1);
            const float lse = mx + LN2 * flog2(1.f + fexp2(LOG2E * (mn - mx)));
            lp += (sp ? o1 : o0) - lse;
        }
    }
    lp += __shfl_xor(lp, 16, 64);   // reduce over oct
    lp += __shfl_xor(lp, 32, 64);
    lp += __shfl_xor(lp, 8, 64);    // reduce over unit-half chunk
    if (lane < 8) red[w][lane] = lp;
    __syncthreads();
    if (tid < 8) {
        float s = 0.f;
#pragma unroll
        for (int ww = 0; ww < 4; ++ww) s += red[ww][tid];
        out[b0 + tid] = 0.5f * s;
    }
}

extern "C" void kernel_launch(void* const* d_in, const int* in_sizes, int n_in,
                              void* d_out, int out_size, void* d_ws, size_t ws_size,
                              hipStream_t stream) {
    const int*   x  = (const int*)d_in[0];
    const float* Wi = (const float*)d_in[1];
    const float* Wh = (const float*)d_in[2];
    const float* bh = (const float*)d_in[3];
    const float* Wo = (const float*)d_in[4];
    const float* bo = (const float*)d_in[5];
    float* out = (float*)d_out;

    // 512 four-wave WGs; 60.8KB genuinely-allocated LDS/WG -> exactly 2
    // WGs/CU (3x impossible), grid 512 = 2 x 256 CUs uniform. 8 waves/CU =
    // 2 independent-WG waves per SIMD.
    lstm_r17<<<dim3(Bsz / 8), dim3(256), 0, stream>>>(x, Wi, Wh, bh, Wo, bo, out);
}

// Round 8
// 131.596 us; speedup vs baseline: 1.2988x; 1.0404x over previous
//
#include <hip/hip_runtime.h>

// R18: R17 trimmed. B=4096, L=256, H=32, D=2. 512 WGs x 256 threads,
// exactly 2 WGs/CU (Sbuf-pad verified in R17: LDS_Block_Size 60928).
// R17 post-mortem: sleep-seeding + setprio + guaranteed placement all NULL
// (84.5us == R12 exactly) -> the 787cyc step wall is arbitration-proof.
// This round: pure issue diet on the same structure.
//  - removed s_sleep / s_setprio (measured null; 2 SALU/step saved).
//  - 4-step unroll: one aligned ds_read_b32 spin fetch per 4 steps
//    (was 2x ds_read_u16), half the loop branches.
//  - head-logit block moved AFTER the gate extract (off the critical
//    path between MFMA results and the trans chain).
// Everything else identical to R17: 4-wave WG, dup=2 gate tiles + hi-reg
// cndmask extract, Wo embedded in q=0 tile rows 2-3 (free head logits,
// round-robin by rot), LDS h dbuf with one barrier/step, combined-rcp
// cell (7 transcendentals), cvt_pk_bf16 h pack, post-loop ELU/log-softmax.

typedef __attribute__((ext_vector_type(8))) short bf16x8;
typedef __attribute__((ext_vector_type(4))) float f32x4;

#define LOG2E 1.4426950408889634f
#define LN2   0.6931471805599453f

__device__ __forceinline__ float fexp2(float x) { return __builtin_amdgcn_exp2f(x); }
__device__ __forceinline__ float flog2(float x) { return __builtin_amdgcn_logf(x); }
__device__ __forceinline__ float frcp(float x)  { return __builtin_amdgcn_rcpf(x); }

__device__ __forceinline__ float fsig(float x)   { return frcp(1.f + fexp2(-LOG2E * x)); }
__device__ __forceinline__ float ftanh_(float x) { return 1.f - 2.f * frcp(fexp2(2.f * LOG2E * x) + 1.f); }
__device__ __forceinline__ float felu(float x)   { return x > 0.f ? x : fexp2(LOG2E * x) - 1.f; }

__device__ __forceinline__ unsigned short f2bf(float f) {   // RNE f32->bf16
    unsigned u = __builtin_bit_cast(unsigned, f);
    u = (u + 0x7FFFu + ((u >> 16) & 1u)) >> 16;
    return (unsigned short)u;
}

__device__ __forceinline__ unsigned cvtpk_bf16(float a, float b) {
    unsigned r;
    asm("v_cvt_pk_bf16_f32 %0, %1, %2" : "=v"(r) : "v"(a), "v"(b));
    return r;   // lo16 = bf16(a), hi16 = bf16(b), RNE
}

constexpr int Bsz = 4096;

__global__ __launch_bounds__(256, 2) void lstm_r18(
    const int*   __restrict__ x,    // [B, 256]
    const float* __restrict__ Wi,   // [2, 128]
    const float* __restrict__ Wh,   // [32, 128]
    const float* __restrict__ bh,   // [128]
    const float* __restrict__ Wo,   // [32, 2]
    const float* __restrict__ bo,   // [2]
    float*       __restrict__ out)  // [B]
{
    const int tid  = threadIdx.x;
    const int w    = tid >> 6;      // wave 0..3 == rotation
    const int lane = tid & 63;
    const int m    = lane & 15;     // MFMA column
    const int oct  = lane >> 4;
    const int rot  = w;
    const int mb   = m & 7;         // batch within WG
    const int hi   = m >> 3;        // unit half -> acc reg index
    const int b0   = blockIdx.x * 8;

    __shared__ char   spinT[8][260];      // [batch][t] bytes, padded row
    __shared__ float2 Sbuf[256][28];      // logits in cols 0..7; cols 8..27 =
                                          // occupancy pad (indexed -> kept):
                                          // 60.9KB/WG -> exactly 2 WGs/CU
    __shared__ short  hbuf[2][8][40];     // h dbuf, row stride 80 B
    __shared__ float  red[4][8];

    // ---- stage spins: 256 threads x 8 ints ----
    {
        const int bl = tid >> 5;          // 0..7
        const int c8 = (tid & 31) * 8;
        const int4* src = reinterpret_cast<const int4*>(x + (b0 + bl) * 256 + c8);
        const int4 v0 = src[0], v1 = src[1];
        const int p0 = (v0.x & 1) | ((v0.y & 1) << 8) | ((v0.z & 1) << 16) | ((v0.w & 1) << 24);
        const int p1 = (v1.x & 1) | ((v1.y & 1) << 8) | ((v1.z & 1) << 16) | ((v1.w & 1) << 24);
        *reinterpret_cast<int*>(&spinT[bl][c8])     = p0;
        *reinterpret_cast<int*>(&spinT[bl][c8 + 4]) = p1;
    }

    // ---- weight A-frags: tile q row 4a+r (r=m&3, a=m>>2):
    //   r in {0,1}: gate col 32q + 16r + 4a + rot (scaled)
    //   r in {2,3}, q==0: Wo col r-2 (raw) -> free head logits
    bf16x8 wfrag[4];
#pragma unroll
    for (int q = 0; q < 4; ++q) {
        const float gs = (q == 2) ? 2.f * LOG2E : -LOG2E;
        const int r = m & 3, a = m >> 2;
#pragma unroll
        for (int j = 0; j < 8; ++j) {
            float v = 0.f;
            if (r < 2)          v = gs * Wh[(oct * 8 + j) * 128 + (32 * q + 16 * r + 4 * a + rot)];
            else if (q == 0)    v = Wo[(oct * 8 + j) * 2 + (r - 2)];
            wfrag[q][j] = (short)f2bf(v);
        }
    }

    // ---- this lane's cell + scaled biases ----
    const int ucell = 4 * oct + rot + 16 * hi;
    float bv0[4], bvd[4];
#pragma unroll
    for (int q = 0; q < 4; ++q) {
        const float gs = (q == 2) ? 2.f * LOG2E : -LOG2E;
        const int c0 = 32 * q + ucell;
        bv0[q] = gs * (bh[c0] + Wi[c0]);
        bvd[q] = gs * (Wi[128 + c0] - Wi[c0]);
    }
    const float bo0 = bo[0], bo1 = bo[1];

    // ---- peel t=0: input zeros, h=c=0 -> gates = bh ----
    float c = fsig(bh[ucell]) * ftanh_(bh[64 + ucell]);
    hbuf[0][mb][ucell] = (short)f2bf(fsig(bh[96 + ucell]) * ftanh_(c));
    __syncthreads();

    const int rotS = __builtin_amdgcn_readfirstlane(rot);
    const f32x4 zero4 = { 0.f, 0.f, 0.f, 0.f };

    // one step; rb/wb compile-time at each call site -> static addresses
    auto step = [&](const int t, const int rb, const int wb, const float spf) {
        const bf16x8 hfrag =
            *reinterpret_cast<const bf16x8*>(&hbuf[rb][mb][8 * oct]);

        f32x4 acc[4];
#pragma unroll
        for (int q = 0; q < 4; ++q)
            acc[q] = __builtin_amdgcn_mfma_f32_16x16x32_bf16(wfrag[q], hfrag, zero4, 0, 0, 0);

        // gate extract first (critical path): reg r = hi (one cndmask each)
        const float g0 = hi ? acc[0][1] : acc[0][0];
        const float g1 = hi ? acc[1][1] : acc[1][0];
        const float g2 = hi ? acc[2][1] : acc[2][0];
        const float g3 = hi ? acc[3][1] : acc[3][0];

        // head logits of step t-1 (Wo rows in q=0 tile regs 2,3) - off-path
        if (rotS == ((t - 1) & 3)) {
            if (oct == 0 && m < 8)
                Sbuf[t - 1][m] = make_float2(acc[0][2], acc[0][3]);
        }

        // cell update; e_i=e^{-i}, e_f=e^{-f}, e_g=e^{2g}, e_o=e^{-o};
        // combined reciprocal saves one rcp.
        const float a0 = fmaf(spf, bvd[0], bv0[0]) + g0;
        const float a1 = fmaf(spf, bvd[1], bv0[1]) + g1;
        const float a2 = fmaf(spf, bvd[2], bv0[2]) + g2;
        const float a3 = fmaf(spf, bvd[3], bv0[3]) + g3;
        const float ei = fexp2(a0), ef = fexp2(a1);
        const float eg = fexp2(a2), eo = fexp2(a3);
        const float P = (1.f + ei) * (1.f + eg);
        const float Q = 1.f + ef;
        const float R = frcp(P * Q);
        const float gf  = P * R;                 // 1/(1+ef)
        const float igt = (eg - 1.f) * Q * R;    // sig(i)*tanh(g)
        c = fmaf(gf, c, igt);
        const float ec = fexp2(2.f * LOG2E * c);
        const float h  = (ec - 1.f) * frcp((1.f + eo) * (1.f + ec));
        hbuf[wb][mb][ucell] = (short)cvtpk_bf16(h, h);   // 1-instr RNE pack
        __syncthreads();   // h_t visible to all waves of THIS WG
    };

    // 4-step unroll; spins for steps (tb..tb+3) = bytes (tb-1..tb+2), one
    // aligned dword, prefetched a group ahead. tb-1 % 4 == 0 -> aligned.
    unsigned sp4 = *reinterpret_cast<const unsigned*>(&spinT[mb][0]);
    for (int tb = 1; tb < 253; tb += 4) {
        const unsigned sp4n =
            *reinterpret_cast<const unsigned*>(&spinT[mb][tb + 3]);
        step(tb,     0, 1, (float)(sp4 & 0xFFu));
        step(tb + 1, 1, 0, (float)((sp4 >> 8) & 0xFFu));
        step(tb + 2, 0, 1, (float)((sp4 >> 16) & 0xFFu));
        step(tb + 3, 1, 0, (float)(sp4 >> 24));
        sp4 = sp4n;
    }
    // tail steps 253..255 use spin bytes 252..254 = sp4 bytes 0..2
    step(253, 0, 1, (float)(sp4 & 0xFFu));
    step(254, 1, 0, (float)((sp4 >> 8) & 0xFFu));
    step(255, 0, 1, (float)((sp4 >> 16) & 0xFFu));

    // ---- tail: head logits of step 255 (h_255 in hbuf[1]) ----
    if (rotS == 0) {
        const bf16x8 hfrag = *reinterpret_cast<const bf16x8*>(&hbuf[1][mb][8 * oct]);
        const f32x4 hs =
            __builtin_amdgcn_mfma_f32_16x16x32_bf16(wfrag[0], hfrag, zero4, 0, 0, 0);
        if (oct == 0 && m < 8) Sbuf[255][m] = make_float2(hs[2], hs[3]);
    }
    __syncthreads();

    // ---- post phase: ELU + log-softmax + sum over t, 32 time-chunks ----
    float lp = 0.f;
    {
        const int t0 = ((w * 4 + oct) * 2 + hi) * 8;
#pragma unroll
        for (int i = 0; i < 8; ++i) {
            const int t = t0 + i;
            const float2 sv = Sbuf[t][mb];
            const int sp = spinT[mb][t];
            const float o0 = felu(sv.x + bo0);
            const float o1 = felu(sv.y + bo1);
            const float mx = fmaxf(o0, o1), mn = fminf(o0, o1);
            const float lse = mx + LN2 * flog2(1.f + fexp2(LOG2E * (mn - mx)));
            lp += (sp ? o1 : o0) - lse;
        }
    }
    lp += __shfl_xor(lp, 16, 64);   // reduce over oct
    lp += __shfl_xor(lp, 32, 64);
    lp += __shfl_xor(lp, 8, 64);    // reduce over unit-half chunk
    if (lane < 8) red[w][lane] = lp;
    __syncthreads();
    if (tid < 8) {
        float s = 0.f;
#pragma unroll
        for (int ww = 0; ww < 4; ++ww) s += red[ww][tid];
        out[b0 + tid] = 0.5f * s;
    }
}

extern "C" void kernel_launch(void* const* d_in, const int* in_sizes, int n_in,
                              void* d_out, int out_size, void* d_ws, size_t ws_size,
                              hipStream_t stream) {
    const int*   x  = (const int*)d_in[0];
    const float* Wi = (const float*)d_in[1];
    const float* Wh = (const float*)d_in[2];
    const float* bh = (const float*)d_in[3];
    const float* Wo = (const float*)d_in[4];
    const float* bo = (const float*)d_in[5];
    float* out = (float*)d_out;

    // 512 four-wave WGs; 60.9KB LDS/WG -> exactly 2 WGs/CU, grid 512 =
    // 2 x 256 CUs uniform; 2 independent-WG waves per SIMD.
    lstm_r18<<<dim3(Bsz / 8), dim3(256), 0, stream>>>(x, Wi, Wh, bh, Wo, bo, out);
}